// Round 15
// baseline (126.053 us; speedup 1.0000x reference)
//
#include <hip/hip_runtime.h>
#include <hip/hip_bf16.h>
#include <math.h>

// Dtype model (pinned R0-R4): float inputs f32; edge_index int32; d_out read
// as f32: chunk0 = pred f32[0:393216], chunk1 = yg f32[393216:786432]; np
// reference computed from bf16-cast inputs -> bf16 intermediates safe.
//
// R7: spills kill. R9: strided LDS reads = bank conflicts. R10: dense-P MFMA
// agg. R11 (118.6, best): 1-block/graph gat, 3 launches. R12 FAILED (1024thr).
// R13 FAILED (grid.sync >> launch boundaries). R14 FAILED (fewer barriers but
// longer phases). Conclusion: gat is latency-bound at 1 block/CU.
// R15 (this): split each graph across 2 blocks (2 heads each) -> grid 512 x
// 256thr @ <=79KB LDS = 2 blocks/CU. Head-separable math; ELU coupling handled
// at kernel boundaries (gat1 partials summed+ELU'd in gat2 staging; gat2
// partials summed in mlp staging - L2 output has no ELU).

#define N_NODES 16384
#define B_GRAPHS 256
#define K_NODES 64
#define DEG 8
#define NHEADS 4
#define C1 100
#define C2 128
#define IN_F 96
#define HID 64
#define OUT_SZ 24
#define PRED_ELEMS (K_NODES * B_GRAPHS * OUT_SZ)   // 393216

#define W1T_ROWS 448
#define W1T_K    96
#define W2T_ROWS 512
#define W2T_K    128

#define P1N (W1T_ROWS * W1T_K)
#define P2N (W2T_ROWS * W2T_K)
#define F1N (K_NODES * HID * C2)
#define F2N (K_NODES * 32 * HID)
#define YG4 (PRED_ELEMS / 4)
#define WAN (768 + 1024)
#define PREPN (P1N + P2N + F1N + F2N + YG4 + WAN)

using bf16 = __hip_bfloat16;
typedef __attribute__((ext_vector_type(8))) short          frag_ab;
typedef __attribute__((ext_vector_type(4))) float          frag_cd;
typedef unsigned short us8 __attribute__((ext_vector_type(8)));
typedef unsigned short us4 __attribute__((ext_vector_type(4)));

__device__ __forceinline__ float us2f(unsigned short u) {
  return __bfloat162float(__ushort_as_bfloat16(u));
}
__device__ __forceinline__ short f2bf_s(float f) {
  return __builtin_bit_cast(short, __float2bfloat16(f));
}

// ---------------------------------------------------------------------------
// prep (R14, verified): pack W1t/W2t/fw1t/fw2t bf16 + yg + wa GEMVs.
// wa1[k][h] = sum_c W1[k,h*100+c]*a1[h,c]; wa2[k][h] (k<100, padded 128).
// ---------------------------------------------------------------------------
__global__ __launch_bounds__(256)
void prep(const float* __restrict__ W1, const float* __restrict__ W2,
          const float* __restrict__ fw1, const float* __restrict__ fw2,
          const float* __restrict__ y,
          const float* __restrict__ as1, const float* __restrict__ ad1,
          const float* __restrict__ as2, const float* __restrict__ ad2,
          bf16* __restrict__ W1t, bf16* __restrict__ W2t,
          bf16* __restrict__ fw1t, bf16* __restrict__ fw2t,
          float* __restrict__ yg,
          float* __restrict__ wa1s, float* __restrict__ wa1d,
          float* __restrict__ wa2s, float* __restrict__ wa2d) {
  int idx = blockIdx.x * 256 + threadIdx.x;
  if (idx < P1N) {
    int c = idx / W1T_K, k = idx - c * W1T_K;
    W1t[idx] = __float2bfloat16((c < 400) ? W1[(size_t)k * 400 + c] : 0.f);
  } else if (idx < P1N + P2N) {
    int i2 = idx - P1N;
    int c = i2 >> 7, k = i2 & 127;
    W2t[i2] = __float2bfloat16((k < 100) ? W2[(size_t)k * 512 + c] : 0.f);
  } else if (idx < P1N + P2N + F1N) {
    int i2 = idx - P1N - P2N;
    int k = i2 >> 13, r = i2 & 8191, j = r >> 7, i = r & 127;
    fw1t[i2] = __float2bfloat16(fw1[(size_t)k * 8192 + i * 64 + j]);
  } else if (idx < P1N + P2N + F1N + F2N) {
    int i2 = idx - P1N - P2N - F1N;
    int k = i2 >> 11, r = i2 & 2047, q = r >> 6, j = r & 63;
    fw2t[i2] = __float2bfloat16((q < OUT_SZ) ? fw2[(size_t)k * 1536 + j * 24 + q] : 0.f);
  } else if (idx < P1N + P2N + F1N + F2N + YG4) {
    int j = idx - P1N - P2N - F1N - F2N;
    int i = j * 4;
    float4 v = *(const float4*)(y + i);
    v.x = __bfloat162float(__float2bfloat16(v.x));
    v.y = __bfloat162float(__float2bfloat16(v.y));
    v.z = __bfloat162float(__float2bfloat16(v.z));
    v.w = __bfloat162float(__float2bfloat16(v.w));
    *(float4*)(yg + i) = v;
  } else {
    int tw = idx - P1N - P2N - F1N - F2N - YG4;
    if (tw < 768) {
      int k = tw >> 3, h = (tw >> 1) & 3, sd = tw & 1;
      const float* a = sd ? ad1 : as1;
      float s = 0.f;
      for (int c = 0; c < C1; ++c)
        s += W1[(size_t)k * 400 + h * C1 + c] * a[h * C1 + c];
      (sd ? wa1d : wa1s)[k * 4 + h] = s;
    } else if (tw < WAN) {
      int t2 = tw - 768;
      int k = t2 >> 3, h = (t2 >> 1) & 3, sd = t2 & 1;
      float s = 0.f;
      if (k < 100) {
        const float* a = sd ? ad2 : as2;
        for (int c = 0; c < C2; ++c)
          s += W2[(size_t)k * 512 + h * C2 + c] * a[h * C2 + c];
      }
      (sd ? wa2d : wa2s)[k * 4 + h] = s;
    }
  }
}

// ---------------------------------------------------------------------------
// gat1: layer-1 half-graph blocks. grid 512 = (g, half); half owns heads
// {2*half, 2*half+1}. Computes raw 2-head partial sum (no 0.25/bias/ELU) ->
// h1p[half][g*64+n][100] bf16. LDS ~74 KB -> 2 blocks/CU.
// ---------------------------------------------------------------------------
__global__ __launch_bounds__(256)
void gat1(const float* __restrict__ x, const bf16* __restrict__ W1t,
          const int* __restrict__ esrc,
          const float* __restrict__ wa1s_g, const float* __restrict__ wa1d_g,
          bf16* __restrict__ h1p) {
  constexpr int LDA = IN_F + 8;   // 104
  constexpr int LDT = 72;
  __shared__ __align__(16) short          As[64 * LDA];     // 13.3 KB
  __shared__ __align__(16) unsigned short xs[256 * LDT];    // 36.9 KB
  __shared__ __align__(16) short          Ps[2 * 64 * LDT]; // 18.4 KB
  __shared__ float wls[96 * 2], wld[96 * 2];
  __shared__ int   edg[K_NODES * DEG];
  __shared__ float als[64 * 3], ald[64 * 3];

  const int g    = blockIdx.x >> 1;
  const int half = blockIdx.x & 1;
  const int t = threadIdx.x;
  const int wv = t >> 6, l = t & 63, lm = l & 15;
  const int lk = (l >> 4) * 8, rq = (l >> 4) * 4;

  // ---- stage ----
  for (int idx = t; idx < 64 * 24; idx += 256) {
    int m = idx / 24, q = idx - m * 24;
    const float4 v = *(const float4*)(x + ((size_t)(g * 64 + m) * IN_F + q * 4));
    short* d = &As[m * LDA + q * 4];
    d[0] = f2bf_s(v.x); d[1] = f2bf_s(v.y); d[2] = f2bf_s(v.z); d[3] = f2bf_s(v.w);
  }
  if (t < 192) {                       // wa own 2 heads: [k][h] h in {0,1}
    int k = t >> 1, h = t & 1;
    wls[t] = wa1s_g[k * 4 + half * 2 + h];
    wld[t] = wa1d_g[k * 4 + half * 2 + h];
  }
  for (int idx = t; idx < K_NODES * DEG; idx += 256)
    edg[idx] = esrc[g * K_NODES * DEG + idx] & (K_NODES - 1);
  for (int idx = t; idx < 2 * 64 * LDT / 8; idx += 256)
    *(us8*)&Ps[idx * 8] = (us8)0;
  __syncthreads();

  // ---- GEMM (wave = chunk) + logits ----
  {
    const int cg = half * 3 + wv;      // global chunks 0-3 / 3-6 (3 duplicated)
    const int n0 = cg * 64;
    frag_cd acc[4][4] = {};
#pragma unroll
    for (int ks = 0; ks < IN_F; ks += 32) {
      frag_ab b[4];
#pragma unroll
      for (int nt = 0; nt < 4; ++nt)
        b[nt] = *(const frag_ab*)((const short*)W1t +
                                  (size_t)(n0 + nt * 16 + lm) * W1T_K + ks + lk);
#pragma unroll
      for (int mt = 0; mt < 4; ++mt) {
        frag_ab a = *(const frag_ab*)&As[(mt * 16 + lm) * LDA + ks + lk];
#pragma unroll
        for (int nt = 0; nt < 4; ++nt)
          acc[mt][nt] = __builtin_amdgcn_mfma_f32_16x16x32_bf16(a, b[nt],
                                                                acc[mt][nt], 0, 0, 0);
      }
    }
#pragma unroll
    for (int mt = 0; mt < 4; ++mt)
#pragma unroll
      for (int nt = 0; nt < 4; ++nt) {
        us4 o;
#pragma unroll
        for (int r = 0; r < 4; ++r) o[r] = (unsigned short)f2bf_s(acc[mt][nt][r]);
        *(us4*)&xs[(wv * 64 + nt * 16 + lm) * LDT + mt * 16 + rq] = o;
      }
    // logits for own 2 heads: thread = (node, h, s/d)
    const int n = t & 63, h = (t >> 6) & 1, sd = t >> 7;
    const float* w = sd ? wld : wls;
    float s = 0.f;
#pragma unroll
    for (int o = 0; o < 12; ++o) {
      const us8 v = *(const us8*)&((const unsigned short*)As)[n * LDA + o * 8];
#pragma unroll
      for (int j = 0; j < 8; ++j) s += us2f(v[j]) * w[(o * 8 + j) * 2 + h];
    }
    (sd ? ald : als)[n * 3 + h] = s;
  }
  __syncthreads();

  // ---- in-wave softmax (own 16 nodes x 2 heads) + agg partial ----
  {
    const int mw = wv * 16;
    if (l < 32) {
      const int n = mw + (l >> 1), h = l & 1;
      const float ad = ald[n * 3 + h];
      int sv[9]; float a[9];
#pragma unroll
      for (int j = 0; j < 8; ++j) sv[j] = edg[n * DEG + j];
      sv[8] = n;
#pragma unroll
      for (int j = 0; j < 9; ++j) {
        float v = als[sv[j] * 3 + h] + ad;
        a[j] = (v >= 0.f) ? v : 0.2f * v;    // leaky_relu 0.2
      }
      float m = -1e30f;
#pragma unroll
      for (int j = 0; j < 9; ++j) m = fmaxf(m, a[j]);
      float s = 0.f;
#pragma unroll
      for (int j = 0; j < 9; ++j) { a[j] = __expf(a[j] - m); s += a[j]; }
      const float inv = 1.f / (s + 1e-16f);
      short* prow = &Ps[(h * 64 + n) * LDT];
#pragma unroll
      for (int j = 0; j < 9; ++j) {
        float tw = a[j];
#pragma unroll
        for (int i = 0; i < 9; ++i)
          if (i != j && sv[i] == sv[j]) tw += a[i];
        prow[sv[j]] = f2bf_s(tw * inv);      // idempotent dedupe
      }
    }
    frag_cd acc[7] = {};
#pragma unroll
    for (int hh = 0; hh < 2; ++hh) {
      const int lb = (half ? 8 : 0) + hh * C1;   // xs local col base
#pragma unroll
      for (int ks = 0; ks < 64; ks += 32) {
        frag_ab a = *(const frag_ab*)&Ps[(hh * 64 + mw + lm) * LDT + ks + lk];
#pragma unroll
        for (int nt = 0; nt < 7; ++nt) {
          frag_ab b = *(const frag_ab*)&xs[(lb + nt * 16 + lm) * LDT + ks + lk];
          acc[nt] = __builtin_amdgcn_mfma_f32_16x16x32_bf16(a, b, acc[nt], 0, 0, 0);
        }
      }
    }
    bf16* outp = h1p + (size_t)half * N_NODES * C1 + (size_t)(g * 64) * C1;
#pragma unroll
    for (int nt = 0; nt < 7; ++nt) {
      const int c = nt * 16 + lm;
      if (c < C1) {
#pragma unroll
        for (int r = 0; r < 4; ++r)
          outp[(size_t)(mw + rq + r) * C1 + c] = __float2bfloat16(acc[nt][r]);
      }
    }
  }
}

// ---------------------------------------------------------------------------
// gat2: layer-2 half-graph blocks. Stage = sum h1 partials + 0.25 + b1 + ELU.
// Writes h2 partial (0.25*own-2-head sum + (half0: b2)) -> h2p. LDS ~79 KB.
// ---------------------------------------------------------------------------
__global__ __launch_bounds__(256)
void gat2(const bf16* __restrict__ h1p, const bf16* __restrict__ W2t,
          const int* __restrict__ esrc,
          const float* __restrict__ wa2s_g, const float* __restrict__ wa2d_g,
          const float* __restrict__ b1, const float* __restrict__ b2,
          bf16* __restrict__ h2p) {
  constexpr int LDA = 136;
  constexpr int LDT = 72;
  __shared__ __align__(16) short          As[64 * LDA];     // 17.4 KB
  __shared__ __align__(16) unsigned short xs[256 * LDT];    // 36.9 KB
  __shared__ __align__(16) short          Ps[2 * 64 * LDT]; // 18.4 KB
  __shared__ float wls[128 * 2], wld[128 * 2];
  __shared__ float bia2[C2];
  __shared__ int   edg[K_NODES * DEG];
  __shared__ float als[64 * 3], ald[64 * 3];

  const int g    = blockIdx.x >> 1;
  const int half = blockIdx.x & 1;
  const int t = threadIdx.x;
  const int wv = t >> 6, l = t & 63, lm = l & 15;
  const int lk = (l >> 4) * 8, rq = (l >> 4) * 4;

  // ---- stage: h1 = ELU(0.25*(p0+p1) + b1) -> As (bf16, k-pad 128) ----
  {
    const bf16* p0 = h1p + (size_t)(g * 64) * C1;
    const bf16* p1 = h1p + (size_t)N_NODES * C1 + (size_t)(g * 64) * C1;
    for (int idx = t; idx < 64 * 25; idx += 256) {
      int n = idx / 25, q = (idx - n * 25) * 4;
      const us4 a = *(const us4*)((const unsigned short*)p0 + (size_t)n * C1 + q);
      const us4 b = *(const us4*)((const unsigned short*)p1 + (size_t)n * C1 + q);
      const float4 bb = *(const float4*)(b1 + q);
      const float bv[4] = {bb.x, bb.y, bb.z, bb.w};
      short* d = &As[n * LDA + q];
#pragma unroll
      for (int j = 0; j < 4; ++j) {
        float v = 0.25f * (us2f(a[j]) + us2f(b[j])) + bv[j];
        v = (v > 0.f) ? v : (__expf(v) - 1.f);
        d[j] = f2bf_s(v);
      }
    }
    for (int idx = t; idx < 64 * 28; idx += 256) {
      int m = idx / 28, kk = 100 + (idx - m * 28);
      As[m * LDA + kk] = 0;
    }
  }
  {                                    // wa2 own 2 heads (pads zero)
    int k = t >> 1, h = t & 1;
    wls[t] = wa2s_g[k * 4 + half * 2 + h];
    wld[t] = wa2d_g[k * 4 + half * 2 + h];
  }
  if (t < C2) bia2[t] = b2[t];
  for (int idx = t; idx < K_NODES * DEG; idx += 256)
    edg[idx] = esrc[g * K_NODES * DEG + idx] & (K_NODES - 1);
  for (int idx = t; idx < 2 * 64 * LDT / 8; idx += 256)
    *(us8*)&Ps[idx * 8] = (us8)0;
  __syncthreads();

  // ---- GEMM (wave = chunk; half owns chunks 4*half..4*half+3) + logits ----
  {
    const int cg = half * 4 + wv;
    const int n0 = cg * 64;
    frag_cd acc[4][4] = {};
#pragma unroll
    for (int ks = 0; ks < 128; ks += 32) {
      frag_ab b[4];
#pragma unroll
      for (int nt = 0; nt < 4; ++nt)
        b[nt] = *(const frag_ab*)((const short*)W2t +
                                  (size_t)(n0 + nt * 16 + lm) * W2T_K + ks + lk);
#pragma unroll
      for (int mt = 0; mt < 4; ++mt) {
        frag_ab a = *(const frag_ab*)&As[(mt * 16 + lm) * LDA + ks + lk];
#pragma unroll
        for (int nt = 0; nt < 4; ++nt)
          acc[mt][nt] = __builtin_amdgcn_mfma_f32_16x16x32_bf16(a, b[nt],
                                                                acc[mt][nt], 0, 0, 0);
      }
    }
#pragma unroll
    for (int mt = 0; mt < 4; ++mt)
#pragma unroll
      for (int nt = 0; nt < 4; ++nt) {
        us4 o;
#pragma unroll
        for (int r = 0; r < 4; ++r) o[r] = (unsigned short)f2bf_s(acc[mt][nt][r]);
        *(us4*)&xs[(wv * 64 + nt * 16 + lm) * LDT + mt * 16 + rq] = o;
      }
    const int n = t & 63, h = (t >> 6) & 1, sd = t >> 7;
    const float* w = sd ? wld : wls;
    float s = 0.f;
#pragma unroll
    for (int o = 0; o < 16; ++o) {     // K=128 incl. zero pads
      const us8 v = *(const us8*)&((const unsigned short*)As)[n * LDA + o * 8];
#pragma unroll
      for (int j = 0; j < 8; ++j) s += us2f(v[j]) * w[(o * 8 + j) * 2 + h];
    }
    (sd ? ald : als)[n * 3 + h] = s;
  }
  __syncthreads();

  // ---- in-wave softmax + agg partial -> h2p ----
  {
    const int mw = wv * 16;
    if (l < 32) {
      const int n = mw + (l >> 1), h = l & 1;
      const float ad = ald[n * 3 + h];
      int sv[9]; float a[9];
#pragma unroll
      for (int j = 0; j < 8; ++j) sv[j] = edg[n * DEG + j];
      sv[8] = n;
#pragma unroll
      for (int j = 0; j < 9; ++j) {
        float v = als[sv[j] * 3 + h] + ad;
        a[j] = (v >= 0.f) ? v : 0.2f * v;
      }
      float m = -1e30f;
#pragma unroll
      for (int j = 0; j < 9; ++j) m = fmaxf(m, a[j]);
      float s = 0.f;
#pragma unroll
      for (int j = 0; j < 9; ++j) { a[j] = __expf(a[j] - m); s += a[j]; }
      const float inv = 1.f / (s + 1e-16f);
      short* prow = &Ps[(h * 64 + n) * LDT];
#pragma unroll
      for (int j = 0; j < 9; ++j) {
        float tw = a[j];
#pragma unroll
        for (int i = 0; i < 9; ++i)
          if (i != j && sv[i] == sv[j]) tw += a[i];
        prow[sv[j]] = f2bf_s(tw * inv);
      }
    }
    frag_cd acc[8] = {};
#pragma unroll
    for (int hh = 0; hh < 2; ++hh) {
      const int lb = hh * C2;            // local col base (both halves)
#pragma unroll
      for (int ks = 0; ks < 64; ks += 32) {
        frag_ab a = *(const frag_ab*)&Ps[(hh * 64 + mw + lm) * LDT + ks + lk];
#pragma unroll
        for (int nt = 0; nt < 8; ++nt) {
          frag_ab b = *(const frag_ab*)&xs[(lb + nt * 16 + lm) * LDT + ks + lk];
          acc[nt] = __builtin_amdgcn_mfma_f32_16x16x32_bf16(a, b, acc[nt], 0, 0, 0);
        }
      }
    }
    bf16* outp = h2p + (size_t)half * N_NODES * C2 + (size_t)(g * 64) * C2;
#pragma unroll
    for (int nt = 0; nt < 8; ++nt) {
      const int c = nt * 16 + lm;
      const float bc = half ? 0.f : bia2[c];
#pragma unroll
      for (int r = 0; r < 4; ++r)
        outp[(size_t)(mw + rq + r) * C2 + c] = __float2bfloat16(0.25f * acc[nt][r] + bc);
    }
  }
}

// ---------------------------------------------------------------------------
// mlp (R14 structure): grid 512 = (k, ms in [0,8)), 32 rows/block, 2 blk/CU.
// As staged as sum of the two h2 partials.
// ---------------------------------------------------------------------------
__global__ __launch_bounds__(256)
void mlp_mfma(const bf16* __restrict__ h2p,
              const bf16* __restrict__ fw1t, const float* __restrict__ fb1,
              const bf16* __restrict__ fw2t, const float* __restrict__ fb2,
              float* __restrict__ pred) {
  constexpr int LDA = 136;
  constexpr int LDH = 72;
  __shared__ __align__(16) short As[32 * LDA];
  __shared__ __align__(16) short B1[HID * LDA];
  __shared__ __align__(16) short Hs[32 * LDH];
  __shared__ __align__(16) short B2[32 * LDH];
  __shared__ float b1s[HID];
  __shared__ float b2s[32];

  const int k  = blockIdx.x & 63;
  const int ms = blockIdx.x >> 6;
  const int t  = threadIdx.x;

  const unsigned short* p0 = (const unsigned short*)h2p;
  const unsigned short* p1 = p0 + (size_t)N_NODES * C2;
  for (int idx = t; idx < 32 * 16; idx += 256) {
    int r = idx >> 4, o = idx & 15;
    const size_t off = ((size_t)((ms * 32 + r) * K_NODES + k) * C2) + o * 8;
    const us8 a = *(const us8*)(p0 + off);
    const us8 b = *(const us8*)(p1 + off);
    us8 s;
#pragma unroll
    for (int j = 0; j < 8; ++j)
      s[j] = (unsigned short)f2bf_s(us2f(a[j]) + us2f(b[j]));
    *(us8*)&As[r * LDA + o * 8] = s;
  }
  for (int idx = t; idx < HID * 16; idx += 256) {
    int n = idx >> 4, o = idx & 15;
    *(us8*)&B1[n * LDA + o * 8] =
        *(const us8*)((const unsigned short*)fw1t + (size_t)k * 8192 + n * 128 + o * 8);
  }
  for (int idx = t; idx < 32 * 8; idx += 256) {
    int q = idx >> 3, o = idx & 7;
    *(us8*)&B2[q * LDH + o * 8] =
        *(const us8*)((const unsigned short*)fw2t + (size_t)k * 2048 + q * 64 + o * 8);
  }
  if (t < HID) b1s[t] = fb1[k * HID + t];
  if (t >= 64 && t < 96) b2s[t - 64] = (t - 64 < OUT_SZ) ? fb2[k * OUT_SZ + (t - 64)] : 0.f;
  __syncthreads();

  const int wv = t >> 6, l = t & 63, lm = l & 15;
  const int lk = (l >> 4) * 8, rq = (l >> 4) * 4;

  {
    const int mt  = wv & 1;
    const int ntp = wv >> 1;
    frag_cd acc[2] = {};
#pragma unroll
    for (int ks = 0; ks < C2; ks += 32) {
      frag_ab a = *(const frag_ab*)&As[(mt * 16 + lm) * LDA + ks + lk];
#pragma unroll
      for (int u = 0; u < 2; ++u) {
        frag_ab b = *(const frag_ab*)&B1[((ntp * 2 + u) * 16 + lm) * LDA + ks + lk];
        acc[u] = __builtin_amdgcn_mfma_f32_16x16x32_bf16(a, b, acc[u], 0, 0, 0);
      }
    }
#pragma unroll
    for (int u = 0; u < 2; ++u) {
      const int j  = (ntp * 2 + u) * 16 + lm;
      const float bj = b1s[j];
#pragma unroll
      for (int r = 0; r < 4; ++r)
        Hs[(mt * 16 + rq + r) * LDH + j] = f2bf_s(fmaxf(acc[u][r] + bj, 0.f));
    }
  }
  __syncthreads();

  {
    const int mt = wv >> 1;
    const int nt = wv & 1;
    frag_cd acc = {};
#pragma unroll
    for (int ks = 0; ks < HID; ks += 32) {
      frag_ab a = *(const frag_ab*)&Hs[(mt * 16 + lm) * LDH + ks + lk];
      frag_ab b = *(const frag_ab*)&B2[(nt * 16 + lm) * LDH + ks + lk];
      acc = __builtin_amdgcn_mfma_f32_16x16x32_bf16(a, b, acc, 0, 0, 0);
    }
    const int q = nt * 16 + lm;
    if (q < OUT_SZ) {
      const float bq = b2s[q];
#pragma unroll
      for (int r = 0; r < 4; ++r)
        pred[((size_t)k * B_GRAPHS + ms * 32 + mt * 16 + rq + r) * OUT_SZ + q] = acc[r] + bq;
    }
  }
}

// ---------------------------------------------------------------------------
extern "C" void kernel_launch(void* const* d_in, const int* in_sizes, int n_in,
                              void* d_out, int out_size, void* d_ws, size_t ws_size,
                              hipStream_t stream) {
  const float* x   = (const float*)d_in[0];
  const int*   ei  = (const int*)d_in[1];
  const float* y   = (const float*)d_in[3];
  const float* W1  = (const float*)d_in[4];
  const float* as1 = (const float*)d_in[5];
  const float* ad1 = (const float*)d_in[6];
  const float* b1  = (const float*)d_in[7];
  const float* W2  = (const float*)d_in[8];
  const float* as2 = (const float*)d_in[9];
  const float* ad2 = (const float*)d_in[10];
  const float* b2  = (const float*)d_in[11];
  const float* fw1 = (const float*)d_in[12];
  const float* fb1 = (const float*)d_in[13];
  const float* fw2 = (const float*)d_in[14];
  const float* fb2 = (const float*)d_in[15];

  // Workspace (~22 MB): h1p[2], h2p[2], W1t, W2t, fw1t, fw2t, wa
  bf16* h1p   = (bf16*)d_ws;                          // 2 * N * 100
  bf16* h2p   = h1p + (size_t)2 * N_NODES * C1;       // 2 * N * 128
  bf16* W1t   = h2p + (size_t)2 * N_NODES * C2;
  bf16* W2t   = W1t + P1N;
  bf16* fw1t  = W2t + P2N;
  bf16* fw2t  = fw1t + F1N;
  float* wa1s = (float*)(fw2t + F2N);
  float* wa1d = wa1s + 384;
  float* wa2s = wa1d + 384;
  float* wa2d = wa2s + 512;

  float* out = (float*)d_out;

  prep<<<(PREPN + 255) / 256, 256, 0, stream>>>(
      W1, W2, fw1, fw2, y, as1, ad1, as2, ad2,
      W1t, W2t, fw1t, fw2t, out + PRED_ELEMS, wa1s, wa1d, wa2s, wa2d);

  gat1<<<B_GRAPHS * 2, 256, 0, stream>>>(x, W1t, ei, wa1s, wa1d, h1p);
  gat2<<<B_GRAPHS * 2, 256, 0, stream>>>(h1p, W2t, ei, wa2s, wa2d, b1, b2, h2p);

  mlp_mfma<<<K_NODES * 8, 256, 0, stream>>>(h2p, fw1t, fb1, fw2t, fb2, out);
}

// Round 16
// 119.120 us; speedup vs baseline: 1.0582x; 1.0582x over previous
//
#include <hip/hip_runtime.h>
#include <hip/hip_bf16.h>
#include <math.h>

// Dtype model (pinned R0-R4): float inputs f32; edge_index int32; d_out read
// as f32: chunk0 = pred f32[0:393216], chunk1 = yg f32[393216:786432]; np
// reference computed from bf16-cast inputs -> bf16 intermediates safe.
//
// OPTIMIZATION LOG: R7 spills kill. R9 strided LDS reads = bank conflicts.
// R10 dense-P MFMA agg. R11 = BEST (118.6us): per-graph 2-layer gat @512thr,
// 3 launches. R12 (1024thr, 121.3), R13 (cooperative grid.sync, 211),
// R14 (fused phases, 123.1), R15 (2-block head-split, 126.1) ALL WORSE.
// Conclusion: window is dominated by fixed harness costs (268MB ws re-poison
// fill ~41us at HBM ceiling + launch/replay machinery); our kernels sum to
// ~15-20us. This is the R11 configuration, reverted byte-for-byte.

#define N_NODES 16384
#define B_GRAPHS 256
#define K_NODES 64
#define DEG 8
#define NHEADS 4
#define C1 100
#define C2 128
#define IN_F 96
#define HID 64
#define OUT_SZ 24
#define PRED_ELEMS (K_NODES * B_GRAPHS * OUT_SZ)   // 393216

#define W1T_ROWS 448   // 400 cols padded to 7*64
#define W1T_K    96
#define W2T_ROWS 512
#define W2T_K    128   // 100 padded

using bf16 = __hip_bfloat16;
typedef __attribute__((ext_vector_type(8))) short          frag_ab;  // 8 bf16
typedef __attribute__((ext_vector_type(4))) float          frag_cd;  // 4 f32
typedef unsigned short us8 __attribute__((ext_vector_type(8)));      // 16 B
typedef unsigned short us4 __attribute__((ext_vector_type(4)));      // 8 B

__device__ __forceinline__ float us2f(unsigned short u) {
  return __bfloat162float(__ushort_as_bfloat16(u));
}
__device__ __forceinline__ short f2bf_s(float f) {
  return __builtin_bit_cast(short, __float2bfloat16(f));
}

// ---------------------------------------------------------------------------
// prep: pack W1^T/W2^T (bf16, padded, k-contiguous) + yg = float(bf16(y)).
// ---------------------------------------------------------------------------
#define P1N (W1T_ROWS * W1T_K)    // 43008
#define P2N (W2T_ROWS * W2T_K)    // 65536
#define YG4 (PRED_ELEMS / 4)      // 98304

__global__ __launch_bounds__(256)
void prep(const float* __restrict__ W1, const float* __restrict__ W2,
          const float* __restrict__ y,
          bf16* __restrict__ W1t, bf16* __restrict__ W2t,
          float* __restrict__ yg) {
  int idx = blockIdx.x * 256 + threadIdx.x;
  if (idx < P1N) {
    int c = idx / W1T_K, k = idx - c * W1T_K;
    W1t[idx] = __float2bfloat16((c < 400) ? W1[(size_t)k * 400 + c] : 0.f);
  } else if (idx < P1N + P2N) {
    int i2 = idx - P1N;
    int c = i2 >> 7, k = i2 & 127;
    W2t[i2] = __float2bfloat16((k < 100) ? W2[(size_t)k * 512 + c] : 0.f);
  } else {
    int j = idx - P1N - P2N;
    if (j < YG4) {
      int i = j * 4;
      float4 v = *(const float4*)(y + i);
      v.x = __bfloat162float(__float2bfloat16(v.x));
      v.y = __bfloat162float(__float2bfloat16(v.y));
      v.z = __bfloat162float(__float2bfloat16(v.z));
      v.w = __bfloat162float(__float2bfloat16(v.w));
      *(float4*)(yg + i) = v;
    }
  }
}

// ---------------------------------------------------------------------------
// Fused two-layer GAT, one block per graph (grid=256), 512 threads (8 waves).
// LDS (~141 KB): As (A-slab, both layers), xs (xl^T), Ps (4 dense P), params.
// L1: stage x -> As(stride 104); xl1 = As@W1t -> xs^T; logits; softmax -> Ps;
//     agg MFMA -> h1 written into As(stride 136, pads zeroed by spare waves).
// L2: xl2 = As@W2t -> xs^T; logits; softmax -> Ps (same support, no re-zero);
//     agg MFMA -> h2 global (bf16).
// ---------------------------------------------------------------------------
__global__ __launch_bounds__(512)
void gat_fused(const float* __restrict__ x,
               const bf16* __restrict__ W1t, const bf16* __restrict__ W2t,
               const int* __restrict__ esrc,
               const float* __restrict__ as1, const float* __restrict__ ad1,
               const float* __restrict__ b1,
               const float* __restrict__ as2, const float* __restrict__ ad2,
               const float* __restrict__ b2,
               bf16* __restrict__ h2out) {
  constexpr int LDA1 = IN_F + 8;     // 104 (shorts)
  constexpr int LDA2 = 136;          // layer-2 A stride (K=128 + 8)
  constexpr int LDT  = 72;           // xs/Ps row stride (shorts)

  __shared__ __align__(16) short          As[64 * LDA2];          // 17.4 KB
  __shared__ __align__(16) unsigned short xs[512 * LDT];          // 73.7 KB
  __shared__ __align__(16) short          Ps[NHEADS * 64 * LDT];  // 36.9 KB
  __shared__ float avs1[400], avd1[400], avs2[512], avd2[512];
  __shared__ float bia1[C1], bia2[C2];
  __shared__ int   edg[K_NODES * DEG];
  __shared__ float als[64 * 5], ald[64 * 5];

  const int g = blockIdx.x;
  const int t = threadIdx.x;
  const int wv = t >> 6;
  const int l  = t & 63;
  const int lm = l & 15;
  const int lk = (l >> 4) * 8;
  const int rq = (l >> 4) * 4;

  // ================= phase 0: stage =================
  {
    constexpr int QR = IN_F / 4;     // 24 float4 per row
    for (int idx = t; idx < 64 * QR; idx += 512) {
      int m = idx / QR, q = idx - m * QR;
      const float4 v = *(const float4*)(x + ((size_t)(g * 64 + m) * IN_F + q * 4));
      short* d = &As[m * LDA1 + q * 4];
      d[0] = f2bf_s(v.x); d[1] = f2bf_s(v.y); d[2] = f2bf_s(v.z); d[3] = f2bf_s(v.w);
    }
  }
  for (int idx = t; idx < 400; idx += 512) { avs1[idx] = as1[idx]; avd1[idx] = ad1[idx]; }
  { avs2[t] = as2[t]; avd2[t] = ad2[t]; }
  if (t < C1) bia1[t] = b1[t];
  if (t < C2) bia2[t] = b2[t];
  edg[t] = esrc[g * K_NODES * DEG + t] & (K_NODES - 1);
  for (int idx = t; idx < NHEADS * 64 * LDT / 8; idx += 512)
    *(us8*)&Ps[idx * 8] = (us8)0;
  __syncthreads();

  // ---- L1 GEMM: xl1 = As @ W1t -> xs^T (waves 0-6, chunk each) ----
  if (wv < 7) {
    const int n0 = wv * 64;
    frag_cd acc[4][4] = {};
#pragma unroll
    for (int ks = 0; ks < IN_F; ks += 32) {
      frag_ab b[4];
#pragma unroll
      for (int nt = 0; nt < 4; ++nt)
        b[nt] = *(const frag_ab*)((const short*)W1t +
                                  (size_t)(n0 + nt * 16 + lm) * W1T_K + ks + lk);
#pragma unroll
      for (int mt = 0; mt < 4; ++mt) {
        frag_ab a = *(const frag_ab*)&As[(mt * 16 + lm) * LDA1 + ks + lk];
#pragma unroll
        for (int nt = 0; nt < 4; ++nt)
          acc[mt][nt] = __builtin_amdgcn_mfma_f32_16x16x32_bf16(a, b[nt],
                                                                acc[mt][nt], 0, 0, 0);
      }
    }
#pragma unroll
    for (int mt = 0; mt < 4; ++mt)
#pragma unroll
      for (int nt = 0; nt < 4; ++nt) {
        const int c4 = n0 + nt * 16 + lm;
        us4 o;
#pragma unroll
        for (int r = 0; r < 4; ++r) o[r] = (unsigned short)f2bf_s(acc[mt][nt][r]);
        *(us4*)&xs[c4 * LDT + mt * 16 + rq] = o;
      }
  }
  __syncthreads();

  // ---- L1 logits ----
  if (t < 256) {
    const int n = t >> 2, h = t & 3;
    float ss = 0.f, sd = 0.f;
#pragma unroll 4
    for (int c = 0; c < C1; ++c) {
      const float v = us2f(xs[(h * C1 + c) * LDT + n]);
      ss += v * avs1[h * C1 + c];
      sd += v * avd1[h * C1 + c];
    }
    als[n * 5 + h] = ss;
    ald[n * 5 + h] = sd;
  }
  __syncthreads();

  // ---- L1 softmax -> Ps; spare threads zero As2 k-pads ----
  if (t < 256) {
    const int n = t >> 2, h = t & 3;
    const float ad = ald[n * 5 + h];
    int   sv[9];
    float a[9];
#pragma unroll
    for (int j = 0; j < 8; ++j) sv[j] = edg[n * DEG + j];
    sv[8] = n;
#pragma unroll
    for (int j = 0; j < 9; ++j) {
      float v = als[sv[j] * 5 + h] + ad;
      a[j] = (v >= 0.f) ? v : 0.2f * v;       // leaky_relu 0.2
    }
    float m = -1e30f;
#pragma unroll
    for (int j = 0; j < 9; ++j) m = fmaxf(m, a[j]);
    float s = 0.f;
#pragma unroll
    for (int j = 0; j < 9; ++j) { a[j] = __expf(a[j] - m); s += a[j]; }
    const float inv = 1.f / (s + 1e-16f);
    short* prow = &Ps[(h * 64 + n) * LDT];
#pragma unroll
    for (int j = 0; j < 9; ++j) {
      float tw = a[j];
#pragma unroll
      for (int i = 0; i < 9; ++i)
        if (i != j && sv[i] == sv[j]) tw += a[i];
      prow[sv[j]] = f2bf_s(tw * inv);         // idempotent dedupe
    }
  } else {
    // zero As layer-2 k-padding (k = 100..127); As1 content is dead here
    for (int i = t - 256; i < 64 * 28; i += 256) {
      int m = i / 28, kk = 100 + (i - m * 28);
      As[m * LDA2 + kk] = 0;
    }
  }
  __syncthreads();

  // ---- L1 agg: h1 = 0.25*sum_h P_h @ X_h + bias, ELU -> As2 ----
  {
    const int mw = (wv & 3) * 16;
    const int cgi = wv >> 2;
    const int ntb = cgi * 4;
    const int nte = (cgi == 0) ? 4 : 7;       // NT=7 split 4+3
    frag_cd acc[4] = {};
#pragma unroll
    for (int h = 0; h < NHEADS; ++h)
#pragma unroll
      for (int ks = 0; ks < 64; ks += 32) {
        frag_ab a = *(const frag_ab*)&Ps[(h * 64 + mw + lm) * LDT + ks + lk];
        for (int nt = ntb; nt < nte; ++nt) {
          frag_ab b = *(const frag_ab*)&xs[(h * C1 + nt * 16 + lm) * LDT + ks + lk];
          acc[nt - ntb] = __builtin_amdgcn_mfma_f32_16x16x32_bf16(a, b,
                                                                  acc[nt - ntb], 0, 0, 0);
        }
      }
    for (int nt = ntb; nt < nte; ++nt) {
      const int c = nt * 16 + lm;
      if (c < C1) {
        const float bc = bia1[c];
#pragma unroll
        for (int r = 0; r < 4; ++r) {
          float vv = acc[nt - ntb][r] * 0.25f + bc;
          vv = (vv > 0.f) ? vv : (__expf(vv) - 1.f);   // ELU
          As[(mw + rq + r) * LDA2 + c] = f2bf_s(vv);
        }
      }
    }
  }
  __syncthreads();

  // ---- L2 GEMM: xl2 = As @ W2t -> xs^T (8 waves, chunk each) ----
  {
    const int n0 = wv * 64;
    frag_cd acc[4][4] = {};
#pragma unroll
    for (int ks = 0; ks < 128; ks += 32) {
      frag_ab b[4];
#pragma unroll
      for (int nt = 0; nt < 4; ++nt)
        b[nt] = *(const frag_ab*)((const short*)W2t +
                                  (size_t)(n0 + nt * 16 + lm) * W2T_K + ks + lk);
#pragma unroll
      for (int mt = 0; mt < 4; ++mt) {
        frag_ab a = *(const frag_ab*)&As[(mt * 16 + lm) * LDA2 + ks + lk];
#pragma unroll
        for (int nt = 0; nt < 4; ++nt)
          acc[mt][nt] = __builtin_amdgcn_mfma_f32_16x16x32_bf16(a, b[nt],
                                                                acc[mt][nt], 0, 0, 0);
      }
    }
#pragma unroll
    for (int mt = 0; mt < 4; ++mt)
#pragma unroll
      for (int nt = 0; nt < 4; ++nt) {
        const int c4 = n0 + nt * 16 + lm;
        us4 o;
#pragma unroll
        for (int r = 0; r < 4; ++r) o[r] = (unsigned short)f2bf_s(acc[mt][nt][r]);
        *(us4*)&xs[c4 * LDT + mt * 16 + rq] = o;
      }
  }
  __syncthreads();

  // ---- L2 logits ----
  if (t < 256) {
    const int n = t >> 2, h = t & 3;
    float ss = 0.f, sd = 0.f;
#pragma unroll 4
    for (int c = 0; c < C2; ++c) {
      const float v = us2f(xs[(h * C2 + c) * LDT + n]);
      ss += v * avs2[h * C2 + c];
      sd += v * avd2[h * C2 + c];
    }
    als[n * 5 + h] = ss;
    ald[n * 5 + h] = sd;
  }
  __syncthreads();

  // ---- L2 softmax -> Ps (same support; no re-zero) ----
  if (t < 256) {
    const int n = t >> 2, h = t & 3;
    const float ad = ald[n * 5 + h];
    int   sv[9];
    float a[9];
#pragma unroll
    for (int j = 0; j < 8; ++j) sv[j] = edg[n * DEG + j];
    sv[8] = n;
#pragma unroll
    for (int j = 0; j < 9; ++j) {
      float v = als[sv[j] * 5 + h] + ad;
      a[j] = (v >= 0.f) ? v : 0.2f * v;
    }
    float m = -1e30f;
#pragma unroll
    for (int j = 0; j < 9; ++j) m = fmaxf(m, a[j]);
    float s = 0.f;
#pragma unroll
    for (int j = 0; j < 9; ++j) { a[j] = __expf(a[j] - m); s += a[j]; }
    const float inv = 1.f / (s + 1e-16f);
    short* prow = &Ps[(h * 64 + n) * LDT];
#pragma unroll
    for (int j = 0; j < 9; ++j) {
      float tw = a[j];
#pragma unroll
      for (int i = 0; i < 9; ++i)
        if (i != j && sv[i] == sv[j]) tw += a[i];
      prow[sv[j]] = f2bf_s(tw * inv);
    }
  }
  __syncthreads();

  // ---- L2 agg: h2 = 0.25*sum_h P_h @ X_h + bias -> global ----
  {
    const int mw = (wv & 3) * 16;
    const int cgi = wv >> 2;
    const int ntb = cgi * 4;                  // NT=8 split 4+4
    frag_cd acc[4] = {};
#pragma unroll
    for (int h = 0; h < NHEADS; ++h)
#pragma unroll
      for (int ks = 0; ks < 64; ks += 32) {
        frag_ab a = *(const frag_ab*)&Ps[(h * 64 + mw + lm) * LDT + ks + lk];
#pragma unroll
        for (int nt = 0; nt < 4; ++nt) {
          frag_ab b = *(const frag_ab*)&xs[(h * C2 + (ntb + nt) * 16 + lm) * LDT + ks + lk];
          acc[nt] = __builtin_amdgcn_mfma_f32_16x16x32_bf16(a, b, acc[nt], 0, 0, 0);
        }
      }
    unsigned short* outp = (unsigned short*)h2out + (size_t)(g * 64) * C2;
#pragma unroll
    for (int nt = 0; nt < 4; ++nt) {
      const int c = (ntb + nt) * 16 + lm;
      const float bc = bia2[c];
#pragma unroll
      for (int r = 0; r < 4; ++r) {
        float vv = acc[nt][r] * 0.25f + bc;
        outp[(size_t)(mw + rq + r) * C2 + c] = (unsigned short)f2bf_s(vv);
      }
    }
  }
}

// ---------------------------------------------------------------------------
// MFMA MLP head (verified R8/R10). Grid 256 = (k) x (ms).
// ---------------------------------------------------------------------------
__global__ __launch_bounds__(256)
void mlp_mfma(const bf16* __restrict__ h2,
              const float* __restrict__ fw1, const float* __restrict__ fb1,
              const float* __restrict__ fw2, const float* __restrict__ fb2,
              float* __restrict__ pred) {
  constexpr int LDA = C2 + 8;
  constexpr int LDH = HID + 8;
  __shared__ __align__(16) short As[64 * LDA];
  __shared__ __align__(16) short B1[HID * LDA];
  __shared__ __align__(16) short Hs[64 * LDH];
  __shared__ __align__(16) short B2[32 * LDH];
  __shared__ float b1s[HID];
  __shared__ float b2s[32];

  const int k  = blockIdx.x & 63;
  const int ms = blockIdx.x >> 6;
  const int t  = threadIdx.x;

  for (int idx = t; idx < 64 * 16; idx += 256) {
    int r = idx >> 4, o = idx & 15;
    const us8 v = *(const us8*)((const unsigned short*)h2 +
        ((size_t)((ms * 64 + r) * K_NODES + k) * C2) + o * 8);
    *(us8*)&As[r * LDA + o * 8] = v;
  }
  for (int idx = t; idx < C2 * HID; idx += 256) {
    int kk = idx >> 6, n = idx & 63;
    B1[n * LDA + kk] = f2bf_s(fw1[(size_t)k * C2 * HID + kk * HID + n]);
  }
  for (int idx = t; idx < HID * 32; idx += 256) {
    int kk = idx >> 5, n = idx & 31;
    float v = (n < OUT_SZ) ? fw2[(size_t)k * HID * OUT_SZ + kk * OUT_SZ + n] : 0.f;
    B2[n * LDH + kk] = f2bf_s(v);
  }
  if (t < HID) b1s[t] = fb1[k * HID + t];
  if (t < 32)  b2s[t] = (t < OUT_SZ) ? fb2[k * OUT_SZ + t] : 0.f;
  __syncthreads();

  const int wv = t >> 6;
  const int l  = t & 63;
  const int lm = l & 15;
  const int lk = (l >> 4) * 8;
  const int rq = (l >> 4) * 4;

  frag_cd acc[4] = {};
#pragma unroll
  for (int ks = 0; ks < C2; ks += 32) {
    frag_ab a = *(const frag_ab*)&As[(wv * 16 + lm) * LDA + ks + lk];
#pragma unroll
    for (int nt = 0; nt < 4; ++nt) {
      frag_ab b = *(const frag_ab*)&B1[(nt * 16 + lm) * LDA + ks + lk];
      acc[nt] = __builtin_amdgcn_mfma_f32_16x16x32_bf16(a, b, acc[nt], 0, 0, 0);
    }
  }
#pragma unroll
  for (int nt = 0; nt < 4; ++nt) {
    const int j  = nt * 16 + lm;
    const float bj = b1s[j];
#pragma unroll
    for (int r = 0; r < 4; ++r) {
      const int m = wv * 16 + rq + r;
      Hs[m * LDH + j] = f2bf_s(fmaxf(acc[nt][r] + bj, 0.f));
    }
  }
  __syncthreads();

  frag_cd acc2[2] = {};
#pragma unroll
  for (int ks = 0; ks < HID; ks += 32) {
    frag_ab a = *(const frag_ab*)&Hs[(wv * 16 + lm) * LDH + ks + lk];
#pragma unroll
    for (int nt = 0; nt < 2; ++nt) {
      frag_ab b = *(const frag_ab*)&B2[(nt * 16 + lm) * LDH + ks + lk];
      acc2[nt] = __builtin_amdgcn_mfma_f32_16x16x32_bf16(a, b, acc2[nt], 0, 0, 0);
    }
  }
#pragma unroll
  for (int nt = 0; nt < 2; ++nt) {
    const int q = nt * 16 + lm;
    if (q < OUT_SZ) {
      const float bq = b2s[q];
#pragma unroll
      for (int r = 0; r < 4; ++r) {
        const int m = wv * 16 + rq + r;
        pred[((size_t)k * B_GRAPHS + ms * 64 + m) * OUT_SZ + q] = acc2[nt][r] + bq;
      }
    }
  }
}

// ---------------------------------------------------------------------------
extern "C" void kernel_launch(void* const* d_in, const int* in_sizes, int n_in,
                              void* d_out, int out_size, void* d_ws, size_t ws_size,
                              hipStream_t stream) {
  const float* x   = (const float*)d_in[0];
  const int*   ei  = (const int*)d_in[1];    // [2,E]: first E entries = src
  const float* y   = (const float*)d_in[3];
  const float* W1  = (const float*)d_in[4];
  const float* as1 = (const float*)d_in[5];
  const float* ad1 = (const float*)d_in[6];
  const float* b1  = (const float*)d_in[7];
  const float* W2  = (const float*)d_in[8];
  const float* as2 = (const float*)d_in[9];
  const float* ad2 = (const float*)d_in[10];
  const float* b2  = (const float*)d_in[11];
  const float* fw1 = (const float*)d_in[12];
  const float* fb1 = (const float*)d_in[13];
  const float* fw2 = (const float*)d_in[14];
  const float* fb2 = (const float*)d_in[15];

  // Workspace: h2, W1t, W2t  (~4.4 MB)
  bf16* h2  = (bf16*)d_ws;
  bf16* W1t = h2 + (size_t)N_NODES * C2;
  bf16* W2t = W1t + P1N;

  float* out = (float*)d_out;

  // ---- prep: pack W^T + yg (all independent) ----
  prep<<<(P1N + P2N + YG4 + 255) / 256, 256, 0, stream>>>(
      W1, W2, y, W1t, W2t, out + PRED_ELEMS);

  // ---- fused two-layer GAT -> h2 ----
  gat_fused<<<B_GRAPHS, 512, 0, stream>>>(x, W1t, W2t, ei,
                                          as1, ad1, b1, as2, ad2, b2, h2);

  // ---- MFMA MLP head -> pred (chunk0, f32) ----
  mlp_mfma<<<K_NODES * 4, 256, 0, stream>>>(h2, fw1, fb1, fw2, fb2, out);
}